// Round 12
// baseline (265.795 us; speedup 1.0000x reference)
//
#include <hip/hip_runtime.h>
#include <hip/hip_bf16.h>

// Problem constants (B=2, S=2048, E=1024, H=16, DH=64)
constexpr int kB   = 2;
constexpr int kS   = 2048;
constexpr int kE   = 1024;
constexpr int kH   = 16;
constexpr int kDH  = 64;
constexpr int kTok = kB * kS;   // 4096 rows total

constexpr float kLog2e = 1.4426950408889634f;

typedef short bf16x8 __attribute__((ext_vector_type(8)));
typedef float f32x4  __attribute__((ext_vector_type(4)));
typedef unsigned int uint2v __attribute__((ext_vector_type(2)));

__device__ __forceinline__ float bf2f(unsigned short s) {
  union { unsigned int u; float f; } c; c.u = ((unsigned int)s) << 16; return c.f;
}
__device__ __forceinline__ unsigned short f2bf(float f) {
  union { float f; unsigned int u; } c; c.f = f;
  unsigned int u = c.u;
  u += 0x7fffu + ((u >> 16) & 1u);   // round-to-nearest-even
  return (unsigned short)(u >> 16);
}

// packed f32x2 -> bf16x2 in one VALU op (T12 recipe; no builtin on gfx950)
__device__ __forceinline__ unsigned cvtpk(float lo, float hi) {
  unsigned r;
  asm("v_cvt_pk_bf16_f32 %0, %1, %2" : "=v"(r) : "v"(lo), "v"(hi));
  return r;
}

// fast 2^x: v_exp_f32 is natively base-2 on gfx9+
__device__ __forceinline__ float fexp2(float x) {
  float r;
  asm("v_exp_f32 %0, %1" : "=v"(r) : "v"(x));
  return r;
}

// async 16B global -> LDS (wave-uniform base + lane*16; m97 pattern)
__device__ __forceinline__ void gl_lds16(const unsigned short* g, unsigned short* l) {
  __builtin_amdgcn_global_load_lds(
      (const __attribute__((address_space(1))) unsigned int*)g,
      (__attribute__((address_space(3))) unsigned int*)l, 16, 0, 0);
}

// -------------------------------------------------------------------------
// Dtype probe: flag = 1 -> inputs fp32 (confirmed R3), 0 -> bf16.
// -------------------------------------------------------------------------
__global__ void detect_dtype(const unsigned short* __restrict__ q, int* flag) {
  __shared__ int cnt;
  if (threadIdx.x == 0) cnt = 0;
  __syncthreads();
  int bad = 0;
  for (int i = threadIdx.x; i < 4096; i += 256) {
    unsigned int e = (q[i] >> 7) & 0xFF;
    if (e >= 0xC0) bad++;
  }
  atomicAdd(&cnt, bad);
  __syncthreads();
  if (threadIdx.x == 0) *flag = (cnt > 8) ? 1 : 0;
}

// -------------------------------------------------------------------------
// Canonicalization, R16: WEIGHTS/BIASES ONLY (8 tensors). q/k/v conversion
// is fused into gemm_qkv's A-staging — removes a 72 MB pure-conversion
// pass. Wq/bq pre-scaled by log2(e) for attn's exp2.
// -------------------------------------------------------------------------
struct Seg { const void* src; unsigned short* dst; unsigned int n; unsigned int blk0; };
struct ConvArgs { Seg s[8]; float scale[8]; };

__global__ __launch_bounds__(256) void conv_all(ConvArgs a, const int* __restrict__ flag) {
  const unsigned int bid = blockIdx.x;
  int si = 0;
  #pragma unroll
  for (int i = 1; i < 8; ++i)
    if (bid >= a.s[i].blk0) si = i;
  const Seg sg = a.s[si];
  const float sc = a.scale[si];
  const int i0 = ((int)(bid - sg.blk0) * 256 + threadIdx.x) * 8;
  if (i0 >= (int)sg.n) return;
  if (*flag) {
    const float* s = (const float*)sg.src + i0;
    f32x4 f0 = *(const f32x4*)(s);
    f32x4 f1 = *(const f32x4*)(s + 4);
    bf16x8 v;
    #pragma unroll
    for (int j = 0; j < 4; ++j) v[j]     = (short)f2bf(f0[j] * sc);
    #pragma unroll
    for (int j = 0; j < 4; ++j) v[j + 4] = (short)f2bf(f1[j] * sc);
    *(bf16x8*)&sg.dst[i0] = v;
  } else {
    bf16x8 v = *(const bf16x8*)((const unsigned short*)sg.src + i0);
    if (sc != 1.0f) {
      #pragma unroll
      for (int j = 0; j < 8; ++j)
        v[j] = (short)f2bf(bf2f((unsigned short)v[j]) * sc);
    }
    *(bf16x8*)&sg.dst[i0] = v;
  }
}

// -------------------------------------------------------------------------
// gemm_qkv, R16: fused-conversion A-staging. A (raw q/k/v input, fp32 or
// bf16 per *flag) is reg-staged + RTNE-packed + ds_write'd (double-
// buffered, attn-style: write tile k+1 at top of iter k, prefetch tile
// k+2 into regs); W stays async global_load_lds. Removes the conv_all
// pass over q/k/v entirely. XCD-bijective swizzle (R9).
// -------------------------------------------------------------------------
__global__ __launch_bounds__(256) void gemm_qkv(
    const void* __restrict__ Qraw, const void* __restrict__ Kraw,
    const void* __restrict__ Vraw,
    const unsigned short* __restrict__ Wbase,
    const unsigned short* __restrict__ biasbase,
    unsigned short* __restrict__ Cbase,
    const int* __restrict__ flag)
{
  __shared__ unsigned short As[2 * 128 * 32];
  __shared__ unsigned short Ws[2 * 128 * 32];

  const int bid = blockIdx.x + (blockIdx.y << 3) + (blockIdx.z << 8);
  const int swz = (bid & 7) * 96 + (bid >> 3);
  const int z   = swz >> 8;          // 0..2
  const int rem = swz & 255;
  const int bM  = (rem >> 3) * 128;
  const int bN  = (rem & 7) * 128;

  const void* Ar = (z == 0) ? Qraw : (z == 1) ? Kraw : Vraw;
  const unsigned short* W    = Wbase    + (size_t)z * (kE * kE);
  const unsigned short* bias = biasbase + (size_t)z * kE;
  unsigned short* C          = Cbase    + (size_t)z * (kTok * kE);

  const bool isf32 = (*flag != 0);

  const int tid  = threadIdx.x;
  const int lane = tid & 63;
  const int wv   = tid >> 6;
  const int wm   = (wv >> 1) * 64;
  const int wn   = (wv & 1) * 64;
  const int lr   = lane & 15;
  const int kq   = (lane >> 4) * 8;
  const int r0   = tid >> 2;         // 0..63
  const int c0   = (tid & 3) * 8;    // 0,8,16,24

  const unsigned short* Wg = W + (size_t)(bN + r0) * kE + c0;
  unsigned short* lW = &Ws[tid * 8];
  unsigned short* lA = &As[tid * 8];   // elem r0*32 + c0

  const float*          Af = (const float*)Ar          + (size_t)(bM + r0) * kE + c0;
  const unsigned short* Ab = (const unsigned short*)Ar + (size_t)(bM + r0) * kE + c0;

  // load + convert one A chunk (rows r0, r0+64; 8 elems at col kk)
  auto loadA = [&](int kk, bf16x8& lo, bf16x8& hi) {
    if (isf32) {
      f32x4 a0 = *(const f32x4*)(Af + kk);
      f32x4 a1 = *(const f32x4*)(Af + kk + 4);
      f32x4 b0 = *(const f32x4*)(Af + (size_t)64 * kE + kk);
      f32x4 b1 = *(const f32x4*)(Af + (size_t)64 * kE + kk + 4);
      #pragma unroll
      for (int j = 0; j < 4; ++j) {
        lo[j]     = (short)f2bf(a0[j]);
        lo[j + 4] = (short)f2bf(a1[j]);
        hi[j]     = (short)f2bf(b0[j]);
        hi[j + 4] = (short)f2bf(b1[j]);
      }
    } else {
      lo = *(const bf16x8*)(Ab + kk);
      hi = *(const bf16x8*)(Ab + (size_t)64 * kE + kk);
    }
  };

  // prologue: A tile0 -> regs -> buf0; W tile0 async; A tile1 -> regs
  bf16x8 rlo, rhi;
  loadA(0, rlo, rhi);
  *(bf16x8*)lA          = rlo;
  *(bf16x8*)(lA + 2048) = rhi;
  gl_lds16(Wg,                    lW);
  gl_lds16(Wg + (size_t)64 * kE,  lW + 2048);
  loadA(32, rlo, rhi);
  __syncthreads();

  f32x4 acc[4][4] = {};
  for (int k0 = 0; k0 < kE; k0 += 32) {
    const int co = ((k0 >> 5) & 1) * 4096;
    const int no = co ^ 4096;
    if (k0 + 32 < kE) {
      // stage tile k+1: A from regs (ds_write), W async
      *(bf16x8*)(lA + no)        = rlo;
      *(bf16x8*)(lA + no + 2048) = rhi;
      gl_lds16(Wg + k0 + 32,                    lW + no);
      gl_lds16(Wg + (size_t)64 * kE + k0 + 32,  lW + no + 2048);
    }
    if (k0 + 64 < kE)
      loadA(k0 + 64, rlo, rhi);   // prefetch tile k+2 into regs

    bf16x8 a[4], b[4];
    #pragma unroll
    for (int i = 0; i < 4; ++i)
      a[i] = *(const bf16x8*)&As[co + (wm + i * 16 + lr) * 32 + kq];
    #pragma unroll
    for (int i = 0; i < 4; ++i)
      b[i] = *(const bf16x8*)&Ws[co + (wn + i * 16 + lr) * 32 + kq];
    #pragma unroll
    for (int i = 0; i < 4; ++i)
      #pragma unroll
      for (int j = 0; j < 4; ++j)
        acc[i][j] = __builtin_amdgcn_mfma_f32_16x16x32_bf16(a[i], b[j], acc[i][j], 0, 0, 0);

    __syncthreads();
  }

  const int qd = lane >> 4;
  #pragma unroll
  for (int j = 0; j < 4; ++j) {
    const int col = bN + wn + j * 16 + lr;
    const float bb = bf2f(bias[col]);
    #pragma unroll
    for (int i = 0; i < 4; ++i)
      #pragma unroll
      for (int r = 0; r < 4; ++r) {
        const int row = bM + wm + i * 16 + qd * 4 + r;
        C[(size_t)row * kE + col] = f2bf(acc[i][j][r] + bb);
      }
  }
}

// -------------------------------------------------------------------------
// BK=64 GEMM core (R14 form) for the 1-block/CU gemm_out: halves barrier
// count; 2-phase double-buffered global_load_lds.
// -------------------------------------------------------------------------
__device__ __forceinline__ void gemm_core64(
    const unsigned short* __restrict__ A,
    const unsigned short* __restrict__ W,
    int Kdim, int bM, int bN,
    unsigned short* As, unsigned short* Ws,
    f32x4 acc[4][4])
{
  const int tid  = threadIdx.x;
  const int lane = tid & 63;
  const int wv   = tid >> 6;
  const int wm   = (wv >> 1) * 64;
  const int wn   = (wv & 1) * 64;
  const int lr   = lane & 15;
  const int kq   = (lane >> 4) * 8;

  const int r0 = tid >> 3;           // 0..31
  const int c0 = (tid & 7) * 8;      // 0..56

  const unsigned short* Ag = A + (size_t)(bM + r0) * Kdim + c0;
  const unsigned short* Wg = W + (size_t)(bN + r0) * Kdim + c0;
  unsigned short* lA = &As[tid * 8];
  unsigned short* lW = &Ws[tid * 8];

  // prologue: stage k0=0 into buf 0 (4 calls/array: rows r0+32j)
  #pragma unroll
  for (int j = 0; j < 4; ++j) {
    gl_lds16(Ag + (size_t)(32 * j) * Kdim, lA + j * 2048);
    gl_lds16(Wg + (size_t)(32 * j) * Kdim, lW + j * 2048);
  }
  __syncthreads();

  for (int k0 = 0; k0 < Kdim; k0 += 64) {
    const int co = ((k0 >> 6) & 1) * 8192;
    if (k0 + 64 < Kdim) {
      const int no = co ^ 8192;
      #pragma unroll
      for (int j = 0; j < 4; ++j) {
        gl_lds16(Ag + (size_t)(32 * j) * Kdim + k0 + 64, lA + no + j * 2048);
        gl_lds16(Wg + (size_t)(32 * j) * Kdim + k0 + 64, lW + no + j * 2048);
      }
    }
    #pragma unroll
    for (int kk2 = 0; kk2 < 2; ++kk2) {
      bf16x8 a[4], b[4];
      #pragma unroll
      for (int i = 0; i < 4; ++i)
        a[i] = *(const bf16x8*)&As[co + (wm + i * 16 + lr) * 64 + kk2 * 32 + kq];
      #pragma unroll
      for (int i = 0; i < 4; ++i)
        b[i] = *(const bf16x8*)&Ws[co + (wn + i * 16 + lr) * 64 + kk2 * 32 + kq];
      #pragma unroll
      for (int i = 0; i < 4; ++i)
        #pragma unroll
        for (int j = 0; j < 4; ++j)
          acc[i][j] = __builtin_amdgcn_mfma_f32_16x16x32_bf16(a[i], b[j], acc[i][j], 0, 0, 0);
    }
    __syncthreads();
  }
}

// -------------------------------------------------------------------------
// Tiled V transpose: [tok 4096][kE] -> [b][kE][kS].
// -------------------------------------------------------------------------
__global__ __launch_bounds__(256) void vtrans(
    const unsigned short* __restrict__ Vb,
    unsigned short* __restrict__ Vt)
{
  __shared__ unsigned short Lt[64 * 72];
  const int tid = threadIdx.x;
  const int bh  = blockIdx.y;
  const int b   = bh >> 4;
  const int h   = bh & 15;
  const int hcol = h * kDH;
  const int s0  = blockIdx.x * 64;

  #pragma unroll
  for (int issue = 0; issue < 2; ++issue) {
    int g = issue * 256 + tid;
    int r = g >> 3, c = (g & 7) * 8;   // r = token-local, c = feat-local
    bf16x8 vv = *(const bf16x8*)&Vb[(size_t)(b * kS + s0 + r) * kE + hcol + c];
    const int swz = ((((r >> 3) ^ (c >> 3)) & 7) << 3) + (r & 7);
    #pragma unroll
    for (int i = 0; i < 8; ++i)
      Lt[(c + i) * 72 + swz] = (unsigned short)vv[i];
  }
  __syncthreads();
  #pragma unroll
  for (int issue = 0; issue < 2; ++issue) {
    int g = issue * 256 + tid;
    int f = g >> 3, tc = (g & 7) * 8;
    const int blk = ((tc >> 3) ^ (f >> 3)) & 7;
    bf16x8 vv = *(const bf16x8*)&Lt[f * 72 + (blk << 3)];
    *(bf16x8*)&Vt[(size_t)b * (kE * kS) + (size_t)(hcol + f) * kS + s0 + tc] = vv;
  }
}

// Output projection: BK=64 core; epilogue writes fp32 when *flag.
__global__ __launch_bounds__(256) void gemm_out(
    const unsigned short* __restrict__ A,
    const unsigned short* __restrict__ W,
    const unsigned short* __restrict__ bias,
    void* __restrict__ C,
    const int* __restrict__ flag)
{
  __shared__ unsigned short As[2 * 128 * 64];
  __shared__ unsigned short Ws[2 * 128 * 64];

  const int bid = blockIdx.x + (blockIdx.y << 3);
  const int swz = (bid & 7) * 32 + (bid >> 3);
  const int bM  = (swz >> 3) * 128;
  const int bN  = (swz & 7) * 128;

  f32x4 acc[4][4] = {};
  gemm_core64(A, W, kE, bM, bN, As, Ws, acc);

  const int lane = threadIdx.x & 63;
  const int wv   = threadIdx.x >> 6;
  const int wm   = (wv >> 1) * 64;
  const int wn   = (wv & 1) * 64;
  const int lr   = lane & 15;
  const int qd   = lane >> 4;
  if (*flag) {
    float* Cf = (float*)C;
    #pragma unroll
    for (int j = 0; j < 4; ++j) {
      const int col = bN + wn + j * 16 + lr;
      const float bb = bf2f(bias[col]);
      #pragma unroll
      for (int i = 0; i < 4; ++i)
        #pragma unroll
        for (int r = 0; r < 4; ++r) {
          const int row = bM + wm + i * 16 + qd * 4 + r;
          Cf[(size_t)row * kE + col] = acc[i][j][r] + bb;
        }
    }
  } else {
    unsigned short* Cb = (unsigned short*)C;
    #pragma unroll
    for (int j = 0; j < 4; ++j) {
      const int col = bN + wn + j * 16 + lr;
      const float bb = bf2f(bias[col]);
      #pragma unroll
      for (int i = 0; i < 4; ++i)
        #pragma unroll
        for (int r = 0; r < 4; ++r) {
          const int row = bM + wm + i * 16 + qd * 4 + r;
          Cb[(size_t)row * kE + col] = f2bf(acc[i][j][r] + bb);
        }
    }
  }
}

// -------------------------------------------------------------------------
// Flash-style fused attention (R14 structure, unchanged — ~54 µs).
// KVBLK=128, rg=2, double-buffered K/V, one barrier per tile, exp2,
// setprio, XCD-bijective swizzle, in-register P pack.
// -------------------------------------------------------------------------
__global__ __launch_bounds__(256) void attn(
    const unsigned short* __restrict__ Qb,
    const unsigned short* __restrict__ Kb,
    const unsigned short* __restrict__ Vt,   // [b][kE][kS]
    unsigned short* __restrict__ Ob)
{
  __shared__ unsigned short Ks[2][128 * 72];   // [t][d], double-buffered
  __shared__ unsigned short Vs[2][64 * 136];   // [d][t], double-buffered

  const int tid  = threadIdx.x;
  const int lane = tid & 63;
  const int w    = tid >> 6;
  const int lr   = lane & 15;
  const int quad = lane >> 4;
  const int kq   = quad * 8;

  // grid (16,32) = 512 blocks; XCD-bijective swizzle, cpx = 64
  const int bid = blockIdx.x + (blockIdx.y << 4);
  const int swz = (bid & 7) * 64 + (bid >> 3);
  const int bh  = swz >> 4;           // b*H + h
  const int b   = bh >> 4;
  const int h   = bh & 15;
  const int q0  = (swz & 15) * 128;

  const size_t rowbase = (size_t)b * kS * kE;
  const int hcol = h * kDH;
  const unsigned short* Vbase = Vt + (size_t)b * (kE * kS) + (size_t)hcol * kS;

  // K staging: rows kr+32j (128 rows), 8 elems at kc
  const int kr = tid >> 3;            // 0..31
  const int kc = (tid & 7) * 8;       // 0..56
  // V staging: row vr (64 rows), cols vc+32j (128 cols)
  const int vr = tid >> 2;            // 0..63
  const int vc = (tid & 3) * 8;       // 0..24

  // Q fragments straight from global (one-time; B-frag layout = A-frag layout)
  bf16x8 aq[2][2];
  #pragma unroll
  for (int rg = 0; rg < 2; ++rg)
    #pragma unroll
    for (int hh = 0; hh < 2; ++hh)
      aq[rg][hh] = *(const bf16x8*)
          &Qb[rowbase + (size_t)(q0 + w * 32 + rg * 16 + lr) * kE + hcol + hh * 32 + kq];

  f32x4 o[2][4] = {};                 // O accum per rg: col=lane&15=d, row=quad*4+r
  float l4[2][4] = {};                // 4 partial row-sum chains per rg (q = lr)

  // prologue: tile 0 -> regs -> buf0; tile 1 -> regs; one barrier
  bf16x8 rk[4], rv[4];
  #pragma unroll
  for (int j = 0; j < 4; ++j) {
    rk[j] = *(const bf16x8*)&Kb[rowbase + (size_t)(kr + 32 * j) * kE + hcol + kc];
    rv[j] = *(const bf16x8*)&Vbase[(size_t)vr * kS + vc + 32 * j];
  }
  #pragma unroll
  for (int j = 0; j < 4; ++j) {
    *(bf16x8*)&Ks[0][(kr + 32 * j) * 72 + kc] = rk[j];
    *(bf16x8*)&Vs[0][vr * 136 + vc + 32 * j]  = rv[j];
  }
  #pragma unroll
  for (int j = 0; j < 4; ++j) {
    rk[j] = *(const bf16x8*)&Kb[rowbase + (size_t)(128 + kr + 32 * j) * kE + hcol + kc];
    rv[j] = *(const bf16x8*)&Vbase[(size_t)vr * kS + 128 + vc + 32 * j];
  }
  __syncthreads();

  for (int t0 = 0; t0 < kS; t0 += 128) {
    const int cur = (t0 >> 7) & 1;
    const int nxt = cur ^ 1;

    // stage tile t+1 into the other buffer (overlaps compute of tile t)
    if (t0 + 128 < kS) {
      #pragma unroll
      for (int j = 0; j < 4; ++j) {
        *(bf16x8*)&Ks[nxt][(kr + 32 * j) * 72 + kc] = rk[j];
        *(bf16x8*)&Vs[nxt][vr * 136 + vc + 32 * j]  = rv[j];
      }
    }
    // prefetch tile t+2 into regs
    if (t0 + 256 < kS) {
      const int t2 = t0 + 256;
      #pragma unroll
      for (int j = 0; j < 4; ++j) {
        rk[j] = *(const bf16x8*)&Kb[rowbase + (size_t)(t2 + kr + 32 * j) * kE + hcol + kc];
        rv[j] = *(const bf16x8*)&Vbase[(size_t)vr * kS + t2 + vc + 32 * j];
      }
    }

    // scores, swapped operands: S^T tiles (t on row dim, q on lanes)
    f32x4 s[2][8];
    #pragma unroll
    for (int rg = 0; rg < 2; ++rg)
      #pragma unroll
      for (int tn = 0; tn < 8; ++tn)
        s[rg][tn] = f32x4{0.f, 0.f, 0.f, 0.f};
    __builtin_amdgcn_s_setprio(1);
    #pragma unroll
    for (int tn = 0; tn < 8; ++tn) {
      const bf16x8 bk0 = *(const bf16x8*)&Ks[cur][(tn * 16 + lr) * 72 + 0 + kq];
      const bf16x8 bk1 = *(const bf16x8*)&Ks[cur][(tn * 16 + lr) * 72 + 32 + kq];
      #pragma unroll
      for (int rg = 0; rg < 2; ++rg) {
        s[rg][tn] = __builtin_amdgcn_mfma_f32_16x16x32_bf16(bk0, aq[rg][0], s[rg][tn], 0, 0, 0);
        s[rg][tn] = __builtin_amdgcn_mfma_f32_16x16x32_bf16(bk1, aq[rg][1], s[rg][tn], 0, 0, 0);
      }
    }
    __builtin_amdgcn_s_setprio(0);

    // exp2 in place (Q pre-scaled by log2e) + partial row-sums
    #pragma unroll
    for (int rg = 0; rg < 2; ++rg)
      #pragma unroll
      for (int tn = 0; tn < 8; ++tn)
        #pragma unroll
        for (int r = 0; r < 4; ++r) {
          const float e = fexp2(s[rg][tn][r]);
          s[rg][tn][r] = e;
          l4[rg][r] += e;
        }

    // Build PV A-frags in-register (per rg, kk=0..3): cvt_pk + permlane
    bf16x8 ap[2][4];
    #pragma unroll
    for (int rg = 0; rg < 2; ++rg)
      #pragma unroll
      for (int kk = 0; kk < 4; ++kk) {
        const unsigned A0 = cvtpk(s[rg][2 * kk][0],     s[rg][2 * kk][1]);
        const unsigned A1 = cvtpk(s[rg][2 * kk + 1][0], s[rg][2 * kk + 1][1]);
        const uint2v u   = __builtin_amdgcn_permlane32_swap(A0, A1, false, false);
        const uint2v z02 = __builtin_amdgcn_permlane16_swap(u[0], u[1], false, false);
        const unsigned B0 = cvtpk(s[rg][2 * kk][2],     s[rg][2 * kk][3]);
        const unsigned B1 = cvtpk(s[rg][2 * kk + 1][2], s[rg][2 * kk + 1][3]);
        const uint2v v2  = __builtin_amdgcn_permlane32_swap(B0, B1, false, false);
        const uint2v z13 = __builtin_amdgcn_permlane16_swap(v2[0], v2[1], false, false);
        union { unsigned ud[4]; bf16x8 v; } pk;
        pk.ud[0] = z02[0];   // dword m=0: t = kk*32 + quad*8 + 0,1
        pk.ud[1] = z13[0];   // dword m=1: t = kk*32 + quad*8 + 2,3
        pk.ud[2] = z02[1];   // dword m=2: t = kk*32 + quad*8 + 4,5
        pk.ud[3] = z13[1];   // dword m=3: t = kk*32 + quad*8 + 6,7
        ap[rg][kk] = pk.v;
      }

    // PV: O += P @ V   (each bv feeds both rg groups)
    __builtin_amdgcn_s_setprio(1);
    #pragma unroll
    for (int kk = 0; kk < 4; ++kk)
      #pragma unroll
      for (int dt = 0; dt < 4; ++dt) {
        const bf16x8 bv = *(const bf16x8*)&Vs[cur][(dt * 16 + lr) * 136 + kk * 32 + kq];
        #pragma unroll
        for (int rg = 0; rg < 2; ++rg)
          o[rg][dt] = __builtin_amdgcn_mfma_f32_16x16x32_bf16(ap[rg][kk], bv, o[rg][dt], 0, 0, 0);
      }
    __builtin_amdgcn_s_setprio(0);

    __syncthreads();   // single barrier: nxt writes visible; cur reads done
  }

  // final l per rg: combine 4 chains, then the quad-complement halves
  #pragma unroll
  for (int rg = 0; rg < 2; ++rg) {
    float l = (l4[rg][0] + l4[rg][1]) + (l4[rg][2] + l4[rg][3]);
    l += __shfl_xor(l, 16, 64);
    l += __shfl_xor(l, 32, 64);
    float inv[4];
    #pragma unroll
    for (int r = 0; r < 4; ++r)
      inv[r] = 1.0f / __shfl(l, quad * 4 + r, 64);

    // normalize + store (C-layout): row = q0 + w*32 + rg*16 + quad*4 + r
    #pragma unroll
    for (int dt = 0; dt < 4; ++dt) {
      #pragma unroll
      for (int r = 0; r < 4; ++r) {
        const int row = q0 + w * 32 + rg * 16 + quad * 4 + r;
        const int col = hcol + dt * 16 + lr;
        Ob[rowbase + (size_t)row * kE + col] = f2bf(o[rg][dt][r] * inv[r]);
      }
    }
  }
}

extern "C" void kernel_launch(void* const* d_in, const int* in_sizes, int n_in,
                              void* d_out, int out_size, void* d_ws, size_t ws_size,
                              hipStream_t stream) {
  const int nQKV = kTok * kE;   // 4M elements
  const int nW   = kE * kE;     // 1M elements
  const int nB   = kE;          // 1024

  char* wsb = (char*)d_ws;
  int* flag = (int*)wsb;
  unsigned short* qc  = (unsigned short*)(wsb + 16);
  unsigned short* kc  = qc  + (size_t)nQKV;
  unsigned short* vc  = kc  + (size_t)nQKV;
  unsigned short* Wqc = vc  + (size_t)nQKV;
  unsigned short* Wkc = Wqc + (size_t)nW;
  unsigned short* Wvc = Wkc + (size_t)nW;
  unsigned short* Woc = Wvc + (size_t)nW;
  unsigned short* bqc = Woc + (size_t)nW;
  unsigned short* bkc = bqc + nB;
  unsigned short* bvc = bkc + nB;
  unsigned short* boc = bvc + nB;
  unsigned short* Qb  = boc + nB;
  unsigned short* Kb  = Qb  + (size_t)nQKV;
  unsigned short* Vb  = Kb  + (size_t)nQKV;  // natural [tok][feat] V projection
  unsigned short* Vtb = kc;     // alias: kc unused as conv dst now
  unsigned short* Ob  = qc;     // alias: qc unused as conv dst now

  detect_dtype<<<1, 256, 0, stream>>>((const unsigned short*)d_in[0], flag);

  // canonicalize weights/biases only (q/k/v conversion fused into gemm_qkv)
  ConvArgs ca;
  const void* srcs[8] = { d_in[3], d_in[4], d_in[5], d_in[6],
                          d_in[7], d_in[8], d_in[9], d_in[10] };
  unsigned short* dsts[8] = { Wqc, bqc, Wkc, bkc, Wvc, bvc, Woc, boc };
  const unsigned int ns[8] = { (unsigned)nW, (unsigned)nB, (unsigned)nW, (unsigned)nB,
                               (unsigned)nW, (unsigned)nB, (unsigned)nW, (unsigned)nB };
  unsigned int blk = 0;
  for (int i = 0; i < 8; ++i) {
    ca.s[i].src = srcs[i]; ca.s[i].dst = dsts[i]; ca.s[i].n = ns[i]; ca.s[i].blk0 = blk;
    ca.scale[i] = 1.0f;
    blk += (ns[i] + 2047) / 2048;
  }
  ca.scale[0] = kLog2e;   // Wq
  ca.scale[1] = kLog2e;   // bq
  conv_all<<<blk, 256, 0, stream>>>(ca, flag);

  dim3 blk256(256);
  dim3 gqkv(kE / 128, kTok / 128, 3);   // (8, 32, 3) = 768 blocks
  gemm_qkv<<<gqkv, blk256, 0, stream>>>(d_in[0], d_in[1], d_in[2],
                                        Wqc, bqc, Qb, flag);

  dim3 gvt(kS / 64, kB * kH);           // (32, 32)
  vtrans<<<gvt, blk256, 0, stream>>>(Vb, Vtb);

  dim3 gattn(kS / 128, kB * kH);        // (16, 32) = 512 blocks
  attn<<<gattn, blk256, 0, stream>>>(Qb, Kb, Vtb, Ob);

  dim3 gout(kE / 128, kTok / 128);      // (8, 32)
  gemm_out<<<gout, blk256, 0, stream>>>(Ob, Woc, boc, d_out, flag);
}

// Round 13
// 241.809 us; speedup vs baseline: 1.0992x; 1.0992x over previous
//
#include <hip/hip_runtime.h>
#include <hip/hip_bf16.h>

// Problem constants (B=2, S=2048, E=1024, H=16, DH=64)
constexpr int kB   = 2;
constexpr int kS   = 2048;
constexpr int kE   = 1024;
constexpr int kH   = 16;
constexpr int kDH  = 64;
constexpr int kTok = kB * kS;   // 4096 rows total

constexpr float kLog2e = 1.4426950408889634f;

typedef short bf16x8 __attribute__((ext_vector_type(8)));
typedef short bf16x4 __attribute__((ext_vector_type(4)));
typedef float f32x4  __attribute__((ext_vector_type(4)));
typedef unsigned int uint2v __attribute__((ext_vector_type(2)));

__device__ __forceinline__ float bf2f(unsigned short s) {
  union { unsigned int u; float f; } c; c.u = ((unsigned int)s) << 16; return c.f;
}
__device__ __forceinline__ unsigned short f2bf(float f) {
  union { float f; unsigned int u; } c; c.f = f;
  unsigned int u = c.u;
  u += 0x7fffu + ((u >> 16) & 1u);   // round-to-nearest-even
  return (unsigned short)(u >> 16);
}

// packed f32x2 -> bf16x2 in one VALU op (T12 recipe; no builtin on gfx950)
__device__ __forceinline__ unsigned cvtpk(float lo, float hi) {
  unsigned r;
  asm("v_cvt_pk_bf16_f32 %0, %1, %2" : "=v"(r) : "v"(lo), "v"(hi));
  return r;
}

// fast 2^x: v_exp_f32 is natively base-2 on gfx9+
__device__ __forceinline__ float fexp2(float x) {
  float r;
  asm("v_exp_f32 %0, %1" : "=v"(r) : "v"(x));
  return r;
}

// async 16B global -> LDS (wave-uniform base + lane*16; m97 pattern)
__device__ __forceinline__ void gl_lds16(const unsigned short* g, unsigned short* l) {
  __builtin_amdgcn_global_load_lds(
      (const __attribute__((address_space(1))) unsigned int*)g,
      (__attribute__((address_space(3))) unsigned int*)l, 16, 0, 0);
}

// -------------------------------------------------------------------------
// Dtype probe: flag = 1 -> inputs fp32 (confirmed R3), 0 -> bf16.
// -------------------------------------------------------------------------
__global__ void detect_dtype(const unsigned short* __restrict__ q, int* flag) {
  __shared__ int cnt;
  if (threadIdx.x == 0) cnt = 0;
  __syncthreads();
  int bad = 0;
  for (int i = threadIdx.x; i < 4096; i += 256) {
    unsigned int e = (q[i] >> 7) & 0xFF;
    if (e >= 0xC0) bad++;
  }
  atomicAdd(&cnt, bad);
  __syncthreads();
  if (threadIdx.x == 0) *flag = (cnt > 8) ? 1 : 0;
}

// -------------------------------------------------------------------------
// Fused canonicalization: all 11 tensors -> bf16 in one dispatch (R14 form
// — the R16 fused-conversion A-staging was latency-bound, reverted).
// Wq/bq pre-scaled by log2(e) so attn can use exp2 directly.
// -------------------------------------------------------------------------
struct Seg { const void* src; unsigned short* dst; unsigned int n; unsigned int blk0; };
struct ConvArgs { Seg s[11]; float scale[11]; };

__global__ __launch_bounds__(256) void conv_all(ConvArgs a, const int* __restrict__ flag) {
  const unsigned int bid = blockIdx.x;
  int si = 0;
  #pragma unroll
  for (int i = 1; i < 11; ++i)
    if (bid >= a.s[i].blk0) si = i;
  const Seg sg = a.s[si];
  const float sc = a.scale[si];
  const int i0 = ((int)(bid - sg.blk0) * 256 + threadIdx.x) * 8;
  if (i0 >= (int)sg.n) return;
  if (*flag) {
    const float* s = (const float*)sg.src + i0;
    f32x4 f0 = *(const f32x4*)(s);
    f32x4 f1 = *(const f32x4*)(s + 4);
    bf16x8 v;
    #pragma unroll
    for (int j = 0; j < 4; ++j) v[j]     = (short)f2bf(f0[j] * sc);
    #pragma unroll
    for (int j = 0; j < 4; ++j) v[j + 4] = (short)f2bf(f1[j] * sc);
    *(bf16x8*)&sg.dst[i0] = v;
  } else {
    bf16x8 v = *(const bf16x8*)((const unsigned short*)sg.src + i0);
    if (sc != 1.0f) {
      #pragma unroll
      for (int j = 0; j < 8; ++j)
        v[j] = (short)f2bf(bf2f((unsigned short)v[j]) * sc);
    }
    *(bf16x8*)&sg.dst[i0] = v;
  }
}

// -------------------------------------------------------------------------
// Shared GEMM core: 128x128 tile = A @ W^T, BK=32, global_load_lds width-16.
// 2-phase double-buffered LDS, one barrier per K-step (R9/R14 form).
// -------------------------------------------------------------------------
__device__ __forceinline__ void gemm_core(
    const unsigned short* __restrict__ A,
    const unsigned short* __restrict__ W,
    int Kdim, int bM, int bN,
    unsigned short* As, unsigned short* Ws,
    f32x4 acc[4][4])
{
  const int tid  = threadIdx.x;
  const int lane = tid & 63;
  const int wv   = tid >> 6;
  const int wm   = (wv >> 1) * 64;
  const int wn   = (wv & 1) * 64;
  const int lr   = lane & 15;
  const int kq   = (lane >> 4) * 8;

  const int r0 = tid >> 2;           // 0..63
  const int c0 = (tid & 3) * 8;      // 0,8,16,24

  const unsigned short* Ag = A + (size_t)(bM + r0) * Kdim + c0;
  const unsigned short* Wg = W + (size_t)(bN + r0) * Kdim + c0;
  unsigned short* lA = &As[tid * 8];
  unsigned short* lW = &Ws[tid * 8];

  // prologue: stage k0=0 into buf 0, drain once
  gl_lds16(Ag,                      lA);
  gl_lds16(Ag + (size_t)64 * Kdim,  lA + 2048);
  gl_lds16(Wg,                      lW);
  gl_lds16(Wg + (size_t)64 * Kdim,  lW + 2048);
  __syncthreads();

  for (int k0 = 0; k0 < Kdim; k0 += 32) {
    const int co = ((k0 >> 5) & 1) * 4096;   // current buffer offset
    if (k0 + 32 < Kdim) {
      const int no = co ^ 4096;
      gl_lds16(Ag + k0 + 32,                      lA + no);
      gl_lds16(Ag + (size_t)64 * Kdim + k0 + 32,  lA + no + 2048);
      gl_lds16(Wg + k0 + 32,                      lW + no);
      gl_lds16(Wg + (size_t)64 * Kdim + k0 + 32,  lW + no + 2048);
    }

    bf16x8 a[4], b[4];
    #pragma unroll
    for (int i = 0; i < 4; ++i)
      a[i] = *(const bf16x8*)&As[co + (wm + i * 16 + lr) * 32 + kq];
    #pragma unroll
    for (int i = 0; i < 4; ++i)
      b[i] = *(const bf16x8*)&Ws[co + (wn + i * 16 + lr) * 32 + kq];
    #pragma unroll
    for (int i = 0; i < 4; ++i)
      #pragma unroll
      for (int j = 0; j < 4; ++j)
        acc[i][j] = __builtin_amdgcn_mfma_f32_16x16x32_bf16(a[i], b[j], acc[i][j], 0, 0, 0);

    __syncthreads();
  }
}

// -------------------------------------------------------------------------
// Fused Q/K/V projections (R17): XCD-bijective swizzle; R14 gemm_core.
// z==2 (V projection) fuses the transpose into the epilogue: the 128x128
// tile is staged through LDS (stride 136, ~2-way banks) and written
// directly as Vt[b][feat][tok] with coalesced 256B feature rows — deletes
// the vtrans dispatch and its 32 MB round-trip.
// -------------------------------------------------------------------------
__global__ __launch_bounds__(256) void gemm_qkv(
    const unsigned short* __restrict__ Abase,
    const unsigned short* __restrict__ Wbase,
    const unsigned short* __restrict__ biasbase,
    unsigned short* __restrict__ Cbase,   // Qb / Kb for z<2
    unsigned short* __restrict__ Vt)      // [b][kE][kS] for z==2
{
  __shared__ unsigned short smem[17408];  // loop: As|Ws (16384); epi: 128x136
  unsigned short* As = smem;
  unsigned short* Ws = smem + 8192;

  const int bid = blockIdx.x + (blockIdx.y << 3) + (blockIdx.z << 8);
  const int swz = (bid & 7) * 96 + (bid >> 3);
  const int z   = swz >> 8;          // 0..2
  const int rem = swz & 255;
  const int bM  = (rem >> 3) * 128;
  const int bN  = (rem & 7) * 128;

  const unsigned short* A    = Abase    + (size_t)z * (kTok * kE);
  const unsigned short* W    = Wbase    + (size_t)z * (kE * kE);
  const unsigned short* bias = biasbase + (size_t)z * kE;

  f32x4 acc[4][4] = {};
  gemm_core(A, W, kE, bM, bN, As, Ws, acc);

  const int tid  = threadIdx.x;
  const int lane = tid & 63;
  const int wv   = tid >> 6;
  const int wm   = (wv >> 1) * 64;
  const int wn   = (wv & 1) * 64;
  const int lr   = lane & 15;
  const int qd   = lane >> 4;

  if (z < 2) {
    unsigned short* C = Cbase + (size_t)z * (kTok * kE);
    #pragma unroll
    for (int j = 0; j < 4; ++j) {
      const int col = bN + wn + j * 16 + lr;
      const float bb = bf2f(bias[col]);
      #pragma unroll
      for (int i = 0; i < 4; ++i)
        #pragma unroll
        for (int r = 0; r < 4; ++r) {
          const int row = bM + wm + i * 16 + qd * 4 + r;
          C[(size_t)row * kE + col] = f2bf(acc[i][j][r] + bb);
        }
    }
  } else {
    // V: transpose epilogue. Stage [feat][tok] in LDS (stride 136).
    unsigned short* Lt = smem;
    #pragma unroll
    for (int j = 0; j < 4; ++j) {
      const int col = wn + j * 16 + lr;          // feature-local
      const float bb = bf2f(bias[bN + col]);
      #pragma unroll
      for (int i = 0; i < 4; ++i) {
        const int rb = wm + i * 16 + qd * 4;     // token-local base (4 consec)
        bf16x4 v4;
        #pragma unroll
        for (int r = 0; r < 4; ++r)
          v4[r] = (short)f2bf(acc[i][j][r] + bb);
        *(bf16x4*)&Lt[col * 136 + rb] = v4;      // 8B store, 8B aligned
      }
    }
    __syncthreads();
    const int b2      = bM >> 11;                // token row / kS
    const int tokbase = bM & (kS - 1);
    const int fl = tid >> 4;                     // 0..15
    const int tc = (tid & 15) * 8;               // 0..120
    #pragma unroll
    for (int pass = 0; pass < 8; ++pass) {
      const int f = pass * 16 + fl;
      bf16x8 vv = *(const bf16x8*)&Lt[f * 136 + tc];
      *(bf16x8*)&Vt[(size_t)b2 * (kE * kS) + (size_t)(bN + f) * kS + tokbase + tc] = vv;
    }
  }
}

// -------------------------------------------------------------------------
// BK=64 GEMM core (R14 form) for the 1-block/CU gemm_out: halves barrier
// count; 2-phase double-buffered global_load_lds.
// -------------------------------------------------------------------------
__device__ __forceinline__ void gemm_core64(
    const unsigned short* __restrict__ A,
    const unsigned short* __restrict__ W,
    int Kdim, int bM, int bN,
    unsigned short* As, unsigned short* Ws,
    f32x4 acc[4][4])
{
  const int tid  = threadIdx.x;
  const int lane = tid & 63;
  const int wv   = tid >> 6;
  const int wm   = (wv >> 1) * 64;
  const int wn   = (wv & 1) * 64;
  const int lr   = lane & 15;
  const int kq   = (lane >> 4) * 8;

  const int r0 = tid >> 3;           // 0..31
  const int c0 = (tid & 7) * 8;      // 0..56

  const unsigned short* Ag = A + (size_t)(bM + r0) * Kdim + c0;
  const unsigned short* Wg = W + (size_t)(bN + r0) * Kdim + c0;
  unsigned short* lA = &As[tid * 8];
  unsigned short* lW = &Ws[tid * 8];

  // prologue: stage k0=0 into buf 0 (4 calls/array: rows r0+32j)
  #pragma unroll
  for (int j = 0; j < 4; ++j) {
    gl_lds16(Ag + (size_t)(32 * j) * Kdim, lA + j * 2048);
    gl_lds16(Wg + (size_t)(32 * j) * Kdim, lW + j * 2048);
  }
  __syncthreads();

  for (int k0 = 0; k0 < Kdim; k0 += 64) {
    const int co = ((k0 >> 6) & 1) * 8192;
    if (k0 + 64 < Kdim) {
      const int no = co ^ 8192;
      #pragma unroll
      for (int j = 0; j < 4; ++j) {
        gl_lds16(Ag + (size_t)(32 * j) * Kdim + k0 + 64, lA + no + j * 2048);
        gl_lds16(Wg + (size_t)(32 * j) * Kdim + k0 + 64, lW + no + j * 2048);
      }
    }
    #pragma unroll
    for (int kk2 = 0; kk2 < 2; ++kk2) {
      bf16x8 a[4], b[4];
      #pragma unroll
      for (int i = 0; i < 4; ++i)
        a[i] = *(const bf16x8*)&As[co + (wm + i * 16 + lr) * 64 + kk2 * 32 + kq];
      #pragma unroll
      for (int i = 0; i < 4; ++i)
        b[i] = *(const bf16x8*)&Ws[co + (wn + i * 16 + lr) * 64 + kk2 * 32 + kq];
      #pragma unroll
      for (int i = 0; i < 4; ++i)
        #pragma unroll
        for (int j = 0; j < 4; ++j)
          acc[i][j] = __builtin_amdgcn_mfma_f32_16x16x32_bf16(a[i], b[j], acc[i][j], 0, 0, 0);
    }
    __syncthreads();
  }
}

// Output projection: BK=64 core; epilogue writes fp32 when *flag.
__global__ __launch_bounds__(256) void gemm_out(
    const unsigned short* __restrict__ A,
    const unsigned short* __restrict__ W,
    const unsigned short* __restrict__ bias,
    void* __restrict__ C,
    const int* __restrict__ flag)
{
  __shared__ unsigned short As[2 * 128 * 64];
  __shared__ unsigned short Ws[2 * 128 * 64];

  const int bid = blockIdx.x + (blockIdx.y << 3);
  const int swz = (bid & 7) * 32 + (bid >> 3);
  const int bM  = (swz >> 3) * 128;
  const int bN  = (swz & 7) * 128;

  f32x4 acc[4][4] = {};
  gemm_core64(A, W, kE, bM, bN, As, Ws, acc);

  const int lane = threadIdx.x & 63;
  const int wv   = threadIdx.x >> 6;
  const int wm   = (wv >> 1) * 64;
  const int wn   = (wv & 1) * 64;
  const int lr   = lane & 15;
  const int qd   = lane >> 4;
  if (*flag) {
    float* Cf = (float*)C;
    #pragma unroll
    for (int j = 0; j < 4; ++j) {
      const int col = bN + wn + j * 16 + lr;
      const float bb = bf2f(bias[col]);
      #pragma unroll
      for (int i = 0; i < 4; ++i)
        #pragma unroll
        for (int r = 0; r < 4; ++r) {
          const int row = bM + wm + i * 16 + qd * 4 + r;
          Cf[(size_t)row * kE + col] = acc[i][j][r] + bb;
        }
    }
  } else {
    unsigned short* Cb = (unsigned short*)C;
    #pragma unroll
    for (int j = 0; j < 4; ++j) {
      const int col = bN + wn + j * 16 + lr;
      const float bb = bf2f(bias[col]);
      #pragma unroll
      for (int i = 0; i < 4; ++i)
        #pragma unroll
        for (int r = 0; r < 4; ++r) {
          const int row = bM + wm + i * 16 + qd * 4 + r;
          Cb[(size_t)row * kE + col] = f2bf(acc[i][j][r] + bb);
        }
    }
  }
}

// -------------------------------------------------------------------------
// Flash-style fused attention (R14 structure, unchanged — ~54 µs).
// KVBLK=128, rg=2, double-buffered K/V, one barrier per tile, exp2,
// setprio, XCD-bijective swizzle, in-register P pack.
// -------------------------------------------------------------------------
__global__ __launch_bounds__(256) void attn(
    const unsigned short* __restrict__ Qb,
    const unsigned short* __restrict__ Kb,
    const unsigned short* __restrict__ Vt,   // [b][kE][kS]
    unsigned short* __restrict__ Ob)
{
  __shared__ unsigned short Ks[2][128 * 72];   // [t][d], double-buffered
  __shared__ unsigned short Vs[2][64 * 136];   // [d][t], double-buffered

  const int tid  = threadIdx.x;
  const int lane = tid & 63;
  const int w    = tid >> 6;
  const int lr   = lane & 15;
  const int quad = lane >> 4;
  const int kq   = quad * 8;

  // grid (16,32) = 512 blocks; XCD-bijective swizzle, cpx = 64
  const int bid = blockIdx.x + (blockIdx.y << 4);
  const int swz = (bid & 7) * 64 + (bid >> 3);
  const int bh  = swz >> 4;           // b*H + h
  const int b   = bh >> 4;
  const int h   = bh & 15;
  const int q0  = (swz & 15) * 128;

  const size_t rowbase = (size_t)b * kS * kE;
  const int hcol = h * kDH;
  const unsigned short* Vbase = Vt + (size_t)b * (kE * kS) + (size_t)hcol * kS;

  // K staging: rows kr+32j (128 rows), 8 elems at kc
  const int kr = tid >> 3;            // 0..31
  const int kc = (tid & 7) * 8;       // 0..56
  // V staging: row vr (64 rows), cols vc+32j (128 cols)
  const int vr = tid >> 2;            // 0..63
  const int vc = (tid & 3) * 8;       // 0..24

  // Q fragments straight from global (one-time; B-frag layout = A-frag layout)
  bf16x8 aq[2][2];
  #pragma unroll
  for (int rg = 0; rg < 2; ++rg)
    #pragma unroll
    for (int hh = 0; hh < 2; ++hh)
      aq[rg][hh] = *(const bf16x8*)
          &Qb[rowbase + (size_t)(q0 + w * 32 + rg * 16 + lr) * kE + hcol + hh * 32 + kq];

  f32x4 o[2][4] = {};                 // O accum per rg: col=lane&15=d, row=quad*4+r
  float l4[2][4] = {};                // 4 partial row-sum chains per rg (q = lr)

  // prologue: tile 0 -> regs -> buf0; tile 1 -> regs; one barrier
  bf16x8 rk[4], rv[4];
  #pragma unroll
  for (int j = 0; j < 4; ++j) {
    rk[j] = *(const bf16x8*)&Kb[rowbase + (size_t)(kr + 32 * j) * kE + hcol + kc];
    rv[j] = *(const bf16x8*)&Vbase[(size_t)vr * kS + vc + 32 * j];
  }
  #pragma unroll
  for (int j = 0; j < 4; ++j) {
    *(bf16x8*)&Ks[0][(kr + 32 * j) * 72 + kc] = rk[j];
    *(bf16x8*)&Vs[0][vr * 136 + vc + 32 * j]  = rv[j];
  }
  #pragma unroll
  for (int j = 0; j < 4; ++j) {
    rk[j] = *(const bf16x8*)&Kb[rowbase + (size_t)(128 + kr + 32 * j) * kE + hcol + kc];
    rv[j] = *(const bf16x8*)&Vbase[(size_t)vr * kS + 128 + vc + 32 * j];
  }
  __syncthreads();

  for (int t0 = 0; t0 < kS; t0 += 128) {
    const int cur = (t0 >> 7) & 1;
    const int nxt = cur ^ 1;

    // stage tile t+1 into the other buffer (overlaps compute of tile t)
    if (t0 + 128 < kS) {
      #pragma unroll
      for (int j = 0; j < 4; ++j) {
        *(bf16x8*)&Ks[nxt][(kr + 32 * j) * 72 + kc] = rk[j];
        *(bf16x8*)&Vs[nxt][vr * 136 + vc + 32 * j]  = rv[j];
      }
    }
    // prefetch tile t+2 into regs
    if (t0 + 256 < kS) {
      const int t2 = t0 + 256;
      #pragma unroll
      for (int j = 0; j < 4; ++j) {
        rk[j] = *(const bf16x8*)&Kb[rowbase + (size_t)(t2 + kr + 32 * j) * kE + hcol + kc];
        rv[j] = *(const bf16x8*)&Vbase[(size_t)vr * kS + t2 + vc + 32 * j];
      }
    }

    // scores, swapped operands: S^T tiles (t on row dim, q on lanes)
    f32x4 s[2][8];
    #pragma unroll
    for (int rg = 0; rg < 2; ++rg)
      #pragma unroll
      for (int tn = 0; tn < 8; ++tn)
        s[rg][tn] = f32x4{0.f, 0.f, 0.f, 0.f};
    __builtin_amdgcn_s_setprio(1);
    #pragma unroll
    for (int tn = 0; tn < 8; ++tn) {
      const bf16x8 bk0 = *(const bf16x8*)&Ks[cur][(tn * 16 + lr) * 72 + 0 + kq];
      const bf16x8 bk1 = *(const bf16x8*)&Ks[cur][(tn * 16 + lr) * 72 + 32 + kq];
      #pragma unroll
      for (int rg = 0; rg < 2; ++rg) {
        s[rg][tn] = __builtin_amdgcn_mfma_f32_16x16x32_bf16(bk0, aq[rg][0], s[rg][tn], 0, 0, 0);
        s[rg][tn] = __builtin_amdgcn_mfma_f32_16x16x32_bf16(bk1, aq[rg][1], s[rg][tn], 0, 0, 0);
      }
    }
    __builtin_amdgcn_s_setprio(0);

    // exp2 in place (Q pre-scaled by log2e) + partial row-sums
    #pragma unroll
    for (int rg = 0; rg < 2; ++rg)
      #pragma unroll
      for (int tn = 0; tn < 8; ++tn)
        #pragma unroll
        for (int r = 0; r < 4; ++r) {
          const float e = fexp2(s[rg][tn][r]);
          s[rg][tn][r] = e;
          l4[rg][r] += e;
        }

    // Build PV A-frags in-register (per rg, kk=0..3): cvt_pk + permlane
    bf16x8 ap[2][4];
    #pragma unroll
    for (int rg = 0; rg < 2; ++rg)
      #pragma unroll
      for (int kk = 0; kk < 4; ++kk) {
        const unsigned A0 = cvtpk(s[rg][2 * kk][0],     s[rg][2 * kk][1]);
        const unsigned A1 = cvtpk(s[rg][2 * kk + 1][0], s[rg][2 * kk + 1][1]);
        const uint2v u   = __builtin_amdgcn_permlane32_swap(A0, A1, false, false);
        const uint2v z02 = __builtin_amdgcn_permlane16_swap(u[0], u[1], false, false);
        const unsigned B0 = cvtpk(s[rg][2 * kk][2],     s[rg][2 * kk][3]);
        const unsigned B1 = cvtpk(s[rg][2 * kk + 1][2], s[rg][2 * kk + 1][3]);
        const uint2v v2  = __builtin_amdgcn_permlane32_swap(B0, B1, false, false);
        const uint2v z13 = __builtin_amdgcn_permlane16_swap(v2[0], v2[1], false, false);
        union { unsigned ud[4]; bf16x8 v; } pk;
        pk.ud[0] = z02[0];   // dword m=0: t = kk*32 + quad*8 + 0,1
        pk.ud[1] = z13[0];   // dword m=1: t = kk*32 + quad*8 + 2,3
        pk.ud[2] = z02[1];   // dword m=2: t = kk*32 + quad*8 + 4,5
        pk.ud[3] = z13[1];   // dword m=3: t = kk*32 + quad*8 + 6,7
        ap[rg][kk] = pk.v;
      }

    // PV: O += P @ V   (each bv feeds both rg groups)
    __builtin_amdgcn_s_setprio(1);
    #pragma unroll
    for (int kk = 0; kk < 4; ++kk)
      #pragma unroll
      for (int dt = 0; dt < 4; ++dt) {
        const bf16x8 bv = *(const bf16x8*)&Vs[cur][(dt * 16 + lr) * 136 + kk * 32 + kq];
        #pragma unroll
        for (int rg = 0; rg < 2; ++rg)
          o[rg][dt] = __builtin_amdgcn_mfma_f32_16x16x32_bf16(ap[rg][kk], bv, o[rg][dt], 0, 0, 0);
      }
    __builtin_amdgcn_s_setprio(0);

    __syncthreads();   // single barrier: nxt writes visible; cur reads done
  }

  // final l per rg: combine 4 chains, then the quad-complement halves
  #pragma unroll
  for (int rg = 0; rg < 2; ++rg) {
    float l = (l4[rg][0] + l4[rg][1]) + (l4[rg][2] + l4[rg][3]);
    l += __shfl_xor(l, 16, 64);
    l += __shfl_xor(l, 32, 64);
    float inv[4];
    #pragma unroll
    for (int r = 0; r < 4; ++r)
      inv[r] = 1.0f / __shfl(l, quad * 4 + r, 64);

    // normalize + store (C-layout): row = q0 + w*32 + rg*16 + quad*4 + r
    #pragma unroll
    for (int dt = 0; dt < 4; ++dt) {
      #pragma unroll
      for (int r = 0; r < 4; ++r) {
        const int row = q0 + w * 32 + rg * 16 + quad * 4 + r;
        const int col = hcol + dt * 16 + lr;
        Ob[rowbase + (size_t)row * kE + col] = f2bf(o[rg][dt][r] * inv[r]);
      }
    }
  }
}

extern "C" void kernel_launch(void* const* d_in, const int* in_sizes, int n_in,
                              void* d_out, int out_size, void* d_ws, size_t ws_size,
                              hipStream_t stream) {
  const int nQKV = kTok * kE;   // 4M elements
  const int nW   = kE * kE;     // 1M elements
  const int nB   = kE;          // 1024

  char* wsb = (char*)d_ws;
  int* flag = (int*)wsb;
  unsigned short* qc  = (unsigned short*)(wsb + 16);
  unsigned short* kc  = qc  + (size_t)nQKV;
  unsigned short* vc  = kc  + (size_t)nQKV;
  unsigned short* Wqc = vc  + (size_t)nQKV;
  unsigned short* Wkc = Wqc + (size_t)nW;
  unsigned short* Wvc = Wkc + (size_t)nW;
  unsigned short* Woc = Wvc + (size_t)nW;
  unsigned short* bqc = Woc + (size_t)nW;
  unsigned short* bkc = bqc + nB;
  unsigned short* bvc = bkc + nB;
  unsigned short* boc = bvc + nB;
  unsigned short* Qb  = boc + nB;
  unsigned short* Kb  = Qb  + (size_t)nQKV;
  unsigned short* Vtb = Kb  + (size_t)nQKV;  // V written TRANSPOSED here (old Vb slot)
  unsigned short* Ob  = qc;     // alias: qc dead after gemm_qkv

  detect_dtype<<<1, 256, 0, stream>>>((const unsigned short*)d_in[0], flag);

  ConvArgs ca;
  const void* srcs[11] = { d_in[0], d_in[1], d_in[2], d_in[3], d_in[4], d_in[5],
                           d_in[6], d_in[7], d_in[8], d_in[9], d_in[10] };
  unsigned short* dsts[11] = { qc, kc, vc, Wqc, bqc, Wkc, bkc, Wvc, bvc, Woc, boc };
  const unsigned int ns[11] = { (unsigned)nQKV, (unsigned)nQKV, (unsigned)nQKV,
                                (unsigned)nW, (unsigned)nB, (unsigned)nW, (unsigned)nB,
                                (unsigned)nW, (unsigned)nB, (unsigned)nW, (unsigned)nB };
  unsigned int blk = 0;
  for (int i = 0; i < 11; ++i) {
    ca.s[i].src = srcs[i]; ca.s[i].dst = dsts[i]; ca.s[i].n = ns[i]; ca.s[i].blk0 = blk;
    ca.scale[i] = 1.0f;
    blk += (ns[i] + 2047) / 2048;
  }
  ca.scale[3] = kLog2e;   // Wq
  ca.scale[4] = kLog2e;   // bq
  conv_all<<<blk, 256, 0, stream>>>(ca, flag);

  dim3 blk256(256);
  dim3 gqkv(kE / 128, kTok / 128, 3);   // (8, 32, 3) = 768 blocks
  gemm_qkv<<<gqkv, blk256, 0, stream>>>(qc, Wqc, bqc, Qb, Vtb);

  dim3 gattn(kS / 128, kB * kH);        // (16, 32) = 512 blocks
  attn<<<gattn, blk256, 0, stream>>>(Qb, Kb, Vtb, Ob);

  dim3 gout(kE / 128, kTok / 128);      // (8, 32)
  gemm_out<<<gout, blk256, 0, stream>>>(Ob, Woc, boc, d_out, flag);
}